// Round 2
// baseline (2959.311 us; speedup 1.0000x reference)
//
#include <hip/hip_runtime.h>

#define SS   2048
#define HQ   16
#define HK   2
#define GQ   8      // Hq/Hk
#define DD   128
#define DV   128
#define KS   32
#define ST   16
#define SELB 64
#define TOPN 16
#define WINW 512
#define TT   127    // (S-KS)/ST + 1
#define NSEL 32     // S/SEL
#define SCALE 0.08838834764831845f  // 1/sqrt(128)

// ---------------- kernel 1: compressed K/V blocks ----------------
__global__ __launch_bounds__(128) void k_compress(
    const float* __restrict__ k, const float* __restrict__ v,
    const float* __restrict__ wck, const float* __restrict__ wcv,
    float* __restrict__ cmpk, float* __restrict__ cmpv)
{
    int t = blockIdx.x;      // compressed block
    int n = blockIdx.y;      // kv head
    int d = threadIdx.x;     // 128
    int base = t * ST;
    float ak = 0.f, av = 0.f;
    for (int j = 0; j < KS; ++j) {
        ak += k[((base + j) * HK + n) * DD + d] * wck[j];
        av += v[((base + j) * HK + n) * DV + d] * wcv[j];
    }
    cmpk[(t * HK + n) * DD + d] = ak;
    cmpv[(t * HK + n) * DV + d] = av;
}

// ---------------- kernel 2: compressed attention + block selection ----------------
__global__ __launch_bounds__(256) void k_cmp_attn(
    const float* __restrict__ q,
    const float* __restrict__ cmpk, const float* __restrict__ cmpv,
    float* __restrict__ cmpo, int* __restrict__ selcnt, int* __restrict__ selidx)
{
    int blk = blockIdx.x;           // n*S + s
    int n = blk / SS;
    int s = blk % SS;
    int tid = threadIdx.x;

    __shared__ float qs[GQ][DD];    // 4 KB
    __shared__ float p[GQ][TT];     // ~4 KB
    __shared__ float pslc[NSEL];

    for (int i = tid; i < GQ * DD; i += 256) {
        int g = i >> 7, d = i & 127;
        qs[g][d] = q[(s * HQ + n * GQ + g) * DD + d];
    }
    __syncthreads();

    int tmax = (s >= KS - 1) ? ((s - (KS - 1)) / ST) : -1;
    if (tmax > TT - 1) tmax = TT - 1;

    // scores
    for (int i = tid; i < GQ * TT; i += 256) {
        int g = i / TT, t = i % TT;
        float sc = 0.f;
        if (t <= tmax) {
            const float4* ck = (const float4*)&cmpk[(t * HK + n) * DD];
            const float4* qp = (const float4*)&qs[g][0];
            float a = 0.f;
            #pragma unroll 8
            for (int c = 0; c < DD / 4; ++c) {
                float4 kv = ck[c], qv = qp[c];
                a += qv.x * kv.x + qv.y * kv.y + qv.z * kv.z + qv.w * kv.w;
            }
            sc = a * SCALE;
        }
        p[g][t] = sc;
    }
    __syncthreads();

    // per-group softmax (8 threads, serial over <=127 entries)
    if (tid < GQ) {
        int g = tid;
        if (tmax < 0) {
            for (int t = 0; t < TT; ++t) p[g][t] = 0.f;
        } else {
            float m = -1e30f;
            for (int t = 0; t <= tmax; ++t) m = fmaxf(m, p[g][t]);
            float ssum = 0.f;
            for (int t = 0; t <= tmax; ++t) { float e = __expf(p[g][t] - m); p[g][t] = e; ssum += e; }
            float inv = 1.f / ssum;
            for (int t = 0; t <= tmax; ++t) p[g][t] *= inv;
            for (int t = tmax + 1; t < TT; ++t) p[g][t] = 0.f;
        }
    }
    __syncthreads();

    // cmp_o
    for (int i = tid; i < GQ * DV; i += 256) {
        int g = i >> 7, d = i & 127;
        float acc = 0.f;
        for (int t = 0; t <= tmax; ++t) acc += p[g][t] * cmpv[(t * HK + n) * DV + d];
        cmpo[(s * HQ + n * GQ + g) * DV + d] = acc;
    }

    // selection-block scores: p_slc[m] = sum_g sum_{t maps to m} p[g][t]
    if (tid < NSEL) {
        int m = tid;
        float a = 0.f;
        for (int dt = -1; dt < 4; ++dt) {
            int t = 4 * m + dt;
            if (t < 0 || t >= TT) continue;
            bool maps = (t / 4 == m) || ((t % 4 == 3) && (t / 4 == m - 1));
            if (!maps) continue;
            for (int g = 0; g < GQ; ++g) a += p[g][t];
        }
        pslc[m] = a;
    }
    __syncthreads();

    // top-k exactly as jax.lax.top_k (strict-greater scan => lowest index wins ties)
    if (tid == 0) {
        int cur = s / SELB;
        float score[NSEL];
        for (int m = 0; m < NSEL; ++m) {
            float sv;
            if (m == 0 || m == cur) sv = 1e30f;
            else if (m * SELB <= s) sv = pslc[m];
            else sv = -1e30f;
            score[m] = sv;
        }
        int cnt = 0;
        int* outp = &selidx[(n * SS + s) * TOPN];
        for (int pick = 0; pick < TOPN; ++pick) {
            int best = 0; float bv = -1e31f;
            for (int m = 0; m < NSEL; ++m) {
                if (score[m] > bv) { bv = score[m]; best = m; }
            }
            if (bv > -5e29f) outp[cnt++] = best;
            score[best] = -1e31f;
        }
        selcnt[n * SS + s] = cnt;
    }
}

// ---------------- kernel 3: selected + window attention (all 8 GQA heads per block) ----------------
__global__ __launch_bounds__(256) void k_main(
    const float* __restrict__ q, const float* __restrict__ kk, const float* __restrict__ vv,
    const float* __restrict__ wg, const float* __restrict__ bg,
    const float* __restrict__ cmpo, const int* __restrict__ selcnt, const int* __restrict__ selidx,
    float* __restrict__ out)
{
    int s = blockIdx.x;
    int n = blockIdx.y;
    int tid = threadIdx.x;
    int g = tid >> 5;        // subgroup head 0..7
    int lane = tid & 31;

    __shared__ float qs[GQ][DD];      // 4 KB
    __shared__ float sc[GQ][1024];    // 32 KB
    __shared__ int   jl[1024];        // 4 KB (aliased as osel after PV-A)
    __shared__ float op[2][GQ][DV];   // 8 KB
    __shared__ float sinvA[GQ], sinvB[GQ];
    __shared__ float g3v[GQ][3];
    __shared__ int   sBase[TOPN];
    __shared__ int   sPref[TOPN + 1];
    __shared__ int   shCnt, shTot;

    for (int i = tid; i < GQ * DD; i += 256)
        qs[i >> 7][i & 127] = q[(s * HQ + n * GQ + (i >> 7)) * DD + (i & 127)];

    if (tid == 0) {
        int cnt = selcnt[n * SS + s];
        int tot = 0;
        for (int i = 0; i < cnt; ++i) {
            int b = selidx[(n * SS + s) * TOPN + i];
            int base = b * SELB;
            sBase[i] = base;
            sPref[i] = tot;
            int c = s - base + 1;
            if (c > SELB) c = SELB;
            tot += c;
        }
        sPref[cnt] = tot;
        shCnt = cnt; shTot = tot;
    }
    __syncthreads();
    int cnt = shCnt, tot = shTot;

    for (int f = tid; f < tot; f += 256) {
        int i = 0;
        while (i + 1 < cnt && sPref[i + 1] <= f) ++i;
        jl[f] = sBase[i] + (f - sPref[i]);
    }
    // gate (24 threads, runs while others idle; synced below)
    if (tid < GQ * 3) {
        int gg = tid / 3, c = tid % 3;
        float a = 0.f;
        for (int d2 = 0; d2 < DD; ++d2) a += qs[gg][d2] * wg[d2 * 3 + c];
        a += bg[c];
        g3v[gg][c] = 1.f / (1.f + __expf(-a));
    }
    __syncthreads();

    // ---- phase A: selected-attention scores ----
    {
        const float4* qp = (const float4*)&qs[g][0];
        for (int f = lane; f < tot; f += 32) {
            const float4* kp = (const float4*)&kk[(jl[f] * HK + n) * DD];
            float a = 0.f;
            #pragma unroll 8
            for (int c = 0; c < DD / 4; ++c) {
                float4 kv = kp[c], qv = qp[c];
                a += qv.x * kv.x + qv.y * kv.y + qv.z * kv.z + qv.w * kv.w;
            }
            sc[g][f] = a * SCALE;
        }
    }
    __syncthreads();
    // softmax A (per 32-thread subgroup)
    {
        float m = -1e30f;
        for (int f = lane; f < tot; f += 32) m = fmaxf(m, sc[g][f]);
        #pragma unroll
        for (int o = 16; o > 0; o >>= 1) m = fmaxf(m, __shfl_down(m, o, 32));
        m = __shfl(m, 0, 32);
        float ssum = 0.f;
        for (int f = lane; f < tot; f += 32) { float e = __expf(sc[g][f] - m); sc[g][f] = e; ssum += e; }
        #pragma unroll
        for (int o = 16; o > 0; o >>= 1) ssum += __shfl_down(ssum, o, 32);
        if (lane == 0) sinvA[g] = 1.f / ssum;
    }
    __syncthreads();
    // PV A
    {
        int r = tid >> 7, d = tid & 127;
        float acc[GQ];
        #pragma unroll
        for (int gg = 0; gg < GQ; ++gg) acc[gg] = 0.f;
        for (int f = r; f < tot; f += 2) {
            float vval = vv[(jl[f] * HK + n) * DV + d];
            #pragma unroll
            for (int gg = 0; gg < GQ; ++gg) acc[gg] += sc[gg][f] * vval;
        }
        #pragma unroll
        for (int gg = 0; gg < GQ; ++gg) op[r][gg][d] = acc[gg];
    }
    __syncthreads();
    float* osel = (float*)jl;   // alias: jl dead after PV-A
    for (int i = tid; i < GQ * DV; i += 256) {
        int gg = i >> 7, dd = i & 127;
        osel[gg * DV + dd] = (op[0][gg][dd] + op[1][gg][dd]) * sinvA[gg];
    }
    __syncthreads();

    // ---- phase B: sliding window ----
    int j0 = (s >= WINW) ? (s - WINW) : 0;
    int wcnt = s - j0 + 1;
    {
        const float4* qp = (const float4*)&qs[g][0];
        for (int f = lane; f < wcnt; f += 32) {
            const float4* kp = (const float4*)&kk[((j0 + f) * HK + n) * DD];
            float a = 0.f;
            #pragma unroll 8
            for (int c = 0; c < DD / 4; ++c) {
                float4 kv = kp[c], qv = qp[c];
                a += qv.x * kv.x + qv.y * kv.y + qv.z * kv.z + qv.w * kv.w;
            }
            sc[g][f] = a * SCALE;
        }
    }
    __syncthreads();
    {
        float m = -1e30f;
        for (int f = lane; f < wcnt; f += 32) m = fmaxf(m, sc[g][f]);
        #pragma unroll
        for (int o = 16; o > 0; o >>= 1) m = fmaxf(m, __shfl_down(m, o, 32));
        m = __shfl(m, 0, 32);
        float ssum = 0.f;
        for (int f = lane; f < wcnt; f += 32) { float e = __expf(sc[g][f] - m); sc[g][f] = e; ssum += e; }
        #pragma unroll
        for (int o = 16; o > 0; o >>= 1) ssum += __shfl_down(ssum, o, 32);
        if (lane == 0) sinvB[g] = 1.f / ssum;
    }
    __syncthreads();
    {
        int r = tid >> 7, d = tid & 127;
        float acc[GQ];
        #pragma unroll
        for (int gg = 0; gg < GQ; ++gg) acc[gg] = 0.f;
        for (int f = r; f < wcnt; f += 2) {
            float vval = vv[((j0 + f) * HK + n) * DV + d];
            #pragma unroll
            for (int gg = 0; gg < GQ; ++gg) acc[gg] += sc[gg][f] * vval;
        }
        #pragma unroll
        for (int gg = 0; gg < GQ; ++gg) op[r][gg][d] = acc[gg];
    }
    __syncthreads();
    for (int i = tid; i < GQ * DV; i += 256) {
        int gg = i >> 7, dd = i & 127;
        float ow = (op[0][gg][dd] + op[1][gg][dd]) * sinvB[gg];
        float o = g3v[gg][0] * cmpo[(s * HQ + n * GQ + gg) * DV + dd]
                + g3v[gg][1] * osel[gg * DV + dd]
                + g3v[gg][2] * ow;
        out[(s * HQ + n * GQ + gg) * DV + dd] = o;
    }
}

extern "C" void kernel_launch(void* const* d_in, const int* in_sizes, int n_in,
                              void* d_out, int out_size, void* d_ws, size_t ws_size,
                              hipStream_t stream) {
    const float* q   = (const float*)d_in[0];
    const float* k   = (const float*)d_in[1];
    const float* v   = (const float*)d_in[2];
    const float* wck = (const float*)d_in[3];
    const float* wcv = (const float*)d_in[4];
    const float* wg  = (const float*)d_in[5];
    const float* bg  = (const float*)d_in[6];
    float* out = (float*)d_out;

    float* cmpk   = (float*)d_ws;                       // TT*HK*DD floats
    float* cmpv   = cmpk + TT * HK * DD;                // TT*HK*DV floats
    int*   selcnt = (int*)(cmpv + TT * HK * DV);        // HK*SS ints
    int*   selidx = selcnt + HK * SS;                   // HK*SS*TOPN ints
    float* cmpo   = (float*)(selidx + HK * SS * TOPN);  // SS*HQ*DV floats (16 MB)

    k_compress<<<dim3(TT, HK), 128, 0, stream>>>(k, v, wck, wcv, cmpk, cmpv);
    k_cmp_attn<<<HK * SS, 256, 0, stream>>>(q, cmpk, cmpv, cmpo, selcnt, selidx);
    k_main<<<dim3(SS, HK), 256, 0, stream>>>(q, k, v, wg, bg, cmpo, selcnt, selidx, out);
}

// Round 3
// 714.997 us; speedup vs baseline: 4.1389x; 4.1389x over previous
//
#include <hip/hip_runtime.h>

#define SS   2048
#define HQ   16
#define HK   2
#define GQ   8      // Hq/Hk
#define DD   128
#define DV   128
#define KS   32
#define ST   16
#define SELB 64
#define TOPN 16
#define WINW 512
#define TT   127    // (S-KS)/ST + 1
#define NSEL 32     // S/SEL
#define SCALE 0.08838834764831845f  // 1/sqrt(128)

typedef __attribute__((ext_vector_type(8))) short bf16x8;
typedef __attribute__((ext_vector_type(4))) short short4v;
typedef __attribute__((ext_vector_type(4))) float f32x4;

__device__ __forceinline__ short f2bf(float x) {
    union { float f; unsigned u; } a; a.f = x;
    unsigned r = a.u + 0x7FFFu + ((a.u >> 16) & 1u);
    return (short)(r >> 16);
}

// ---------------- kernel 1: compressed K/V blocks ----------------
__global__ __launch_bounds__(128) void k_compress(
    const float* __restrict__ k, const float* __restrict__ v,
    const float* __restrict__ wck, const float* __restrict__ wcv,
    float* __restrict__ cmpk, float* __restrict__ cmpv)
{
    int t = blockIdx.x;
    int n = blockIdx.y;
    int d = threadIdx.x;
    int base = t * ST;
    float ak = 0.f, av = 0.f;
    for (int j = 0; j < KS; ++j) {
        ak += k[((base + j) * HK + n) * DD + d] * wck[j];
        av += v[((base + j) * HK + n) * DV + d] * wcv[j];
    }
    cmpk[(t * HK + n) * DD + d] = ak;
    cmpv[(t * HK + n) * DV + d] = av;
}

// ---------------- kernel 2: compressed attention + block selection ----------------
__global__ __launch_bounds__(256) void k_cmp_attn(
    const float* __restrict__ q,
    const float* __restrict__ cmpk, const float* __restrict__ cmpv,
    float* __restrict__ cmpo, int* __restrict__ selcnt, int* __restrict__ selidx)
{
    int blk = blockIdx.x;           // n*S + s
    int n = blk / SS;
    int s = blk % SS;
    int tid = threadIdx.x;

    __shared__ float qs[GQ][DD];
    __shared__ float p[GQ][TT];
    __shared__ float pslc[NSEL];

    for (int i = tid; i < GQ * DD; i += 256) {
        int g = i >> 7, d = i & 127;
        qs[g][d] = q[(s * HQ + n * GQ + g) * DD + d];
    }
    __syncthreads();

    int tmax = (s >= KS - 1) ? ((s - (KS - 1)) / ST) : -1;
    if (tmax > TT - 1) tmax = TT - 1;

    for (int i = tid; i < GQ * TT; i += 256) {
        int g = i / TT, t = i % TT;
        float sc = 0.f;
        if (t <= tmax) {
            const float4* ck = (const float4*)&cmpk[(t * HK + n) * DD];
            const float4* qp = (const float4*)&qs[g][0];
            float a = 0.f;
            #pragma unroll 8
            for (int c = 0; c < DD / 4; ++c) {
                float4 kv = ck[c], qv = qp[c];
                a += qv.x * kv.x + qv.y * kv.y + qv.z * kv.z + qv.w * kv.w;
            }
            sc = a * SCALE;
        }
        p[g][t] = sc;
    }
    __syncthreads();

    if (tid < GQ) {
        int g = tid;
        if (tmax < 0) {
            for (int t = 0; t < TT; ++t) p[g][t] = 0.f;
        } else {
            float m = -1e30f;
            for (int t = 0; t <= tmax; ++t) m = fmaxf(m, p[g][t]);
            float ssum = 0.f;
            for (int t = 0; t <= tmax; ++t) { float e = __expf(p[g][t] - m); p[g][t] = e; ssum += e; }
            float inv = 1.f / ssum;
            for (int t = 0; t <= tmax; ++t) p[g][t] *= inv;
            for (int t = tmax + 1; t < TT; ++t) p[g][t] = 0.f;
        }
    }
    __syncthreads();

    for (int i = tid; i < GQ * DV; i += 256) {
        int g = i >> 7, d = i & 127;
        float acc = 0.f;
        for (int t = 0; t <= tmax; ++t) acc += p[g][t] * cmpv[(t * HK + n) * DV + d];
        cmpo[(s * HQ + n * GQ + g) * DV + d] = acc;
    }

    if (tid < NSEL) {
        int m = tid;
        float a = 0.f;
        for (int dt = -1; dt < 4; ++dt) {
            int t = 4 * m + dt;
            if (t < 0 || t >= TT) continue;
            bool maps = (t / 4 == m) || ((t % 4 == 3) && (t / 4 == m - 1));
            if (!maps) continue;
            for (int g = 0; g < GQ; ++g) a += p[g][t];
        }
        pslc[m] = a;
    }
    __syncthreads();

    if (tid == 0) {
        int cur = s / SELB;
        float score[NSEL];
        for (int m = 0; m < NSEL; ++m) {
            float sv;
            if (m == 0 || m == cur) sv = 1e30f;
            else if (m * SELB <= s) sv = pslc[m];
            else sv = -1e30f;
            score[m] = sv;
        }
        int cnt = 0;
        int* outp = &selidx[(n * SS + s) * TOPN];
        for (int pick = 0; pick < TOPN; ++pick) {
            int best = 0; float bv = -1e31f;
            for (int m = 0; m < NSEL; ++m) {
                if (score[m] > bv) { bv = score[m]; best = m; }
            }
            if (bv > -5e29f) outp[cnt++] = best;
            score[best] = -1e31f;
        }
        selcnt[n * SS + s] = cnt;
    }
}

// ---------------- kernel 3: MFMA flash attention for selected + window ----------------
__global__ __launch_bounds__(256) void k_main(
    const float* __restrict__ q, const float* __restrict__ kk, const float* __restrict__ vv,
    const float* __restrict__ wg, const float* __restrict__ bg,
    const float* __restrict__ cmpo, const int* __restrict__ selcnt, const int* __restrict__ selidx,
    float* __restrict__ out)
{
    int s = blockIdx.x;
    int n = blockIdx.y;
    int tid = threadIdx.x;
    int w = tid >> 6;            // wave 0..3
    int lane = tid & 63;
    int quad = lane >> 4;        // 0..3
    int l16 = lane & 15;

    __shared__ int   jl[1024];           // selected token list (padded to x64)
    __shared__ float St[16][68];         // score tile [head][token], pad 4
    __shared__ short Pt[16][72];         // P tile bf16 [head][token], pad 8 (144B rows)
    __shared__ float red[16][4];
    __shared__ float Ssum[16][16];
    __shared__ float mls[16], lls[16], alph[16];
    __shared__ float Osel[GQ][DV];       // pass-A output
    __shared__ float g3v[GQ][3];
    __shared__ int   sBase[TOPN];
    __shared__ int   sPref[TOPN + 1];
    __shared__ int   shCnt, shTot;

    // build selection-block prefix table
    if (tid == 0) {
        int cnt = selcnt[n * SS + s];
        int tot = 0;
        for (int i = 0; i < cnt; ++i) {
            int b = selidx[(n * SS + s) * TOPN + i];
            int base = b * SELB;
            sBase[i] = base;
            sPref[i] = tot;
            int c = s - base + 1;
            if (c > SELB) c = SELB;
            tot += c;
        }
        sPref[cnt] = tot;
        shCnt = cnt; shTot = tot;
    }
    // gating head (24 threads, fp32 exact)
    if (tid < GQ * 3) {
        int gg = tid / 3, c = tid % 3;
        const float* qp = &q[(s * HQ + n * GQ + gg) * DD];
        float a = 0.f;
        for (int d2 = 0; d2 < DD; ++d2) a += qp[d2] * wg[d2 * 3 + c];
        a += bg[c];
        g3v[gg][c] = 1.f / (1.f + __expf(-a));
    }
    __syncthreads();
    int cnt = shCnt, tot = shTot;
    int totPad = (tot + 63) & ~63;

    for (int f = tid; f < totPad; f += 256) {
        int val = 0;
        if (f < tot) {
            int i = 0;
            while (i + 1 < cnt && sPref[i + 1] <= f) ++i;
            val = sBase[i] + (f - sPref[i]);
        }
        jl[f] = val;
    }

    // Q B-fragments (per lane: head l16, feature chains kb*32 + quad*8 + j)
    bf16x8 qb[4];
    {
        int h = l16;
        if (h < GQ) {
            const float* qp = &q[(s * HQ + n * GQ + h) * DD + quad * 8];
            #pragma unroll
            for (int kb = 0; kb < 4; ++kb) {
                float4 x = *(const float4*)(qp + kb * 32);
                float4 y = *(const float4*)(qp + kb * 32 + 4);
                bf16x8 t;
                t[0]=f2bf(x.x); t[1]=f2bf(x.y); t[2]=f2bf(x.z); t[3]=f2bf(x.w);
                t[4]=f2bf(y.x); t[5]=f2bf(y.y); t[6]=f2bf(y.z); t[7]=f2bf(y.w);
                qb[kb] = t;
            }
        } else {
            #pragma unroll
            for (int kb = 0; kb < 4; ++kb) {
                bf16x8 z = {0,0,0,0,0,0,0,0};
                qb[kb] = z;
            }
        }
    }
    int j0 = (s >= WINW) ? (s - WINW) : 0;
    int wcnt = s - j0 + 1;
    __syncthreads();   // jl ready

    f32x4 o0, o1;

    auto run_pass = [&](int ntok, bool useList) {
        f32x4 z = {0.f, 0.f, 0.f, 0.f};
        o0 = z; o1 = z;
        if (tid < 16) { mls[tid] = -1e30f; lls[tid] = 0.f; }
        __syncthreads();

        for (int t0 = 0; t0 < ntok; t0 += 64) {
            // ---- scores: D[token 16][head 16], A = K rows, B = Q ----
            f32x4 acc = z;
            int tokRow = t0 + w * 16 + l16;
            int jt;
            if (useList) jt = jl[tokRow];                       // padded, safe
            else         jt = j0 + (tokRow < ntok ? tokRow : 0);
            const float* kp = &kk[(jt * HK + n) * DD + quad * 8];
            #pragma unroll
            for (int kb = 0; kb < 4; ++kb) {
                float4 x = *(const float4*)(kp + kb * 32);
                float4 y = *(const float4*)(kp + kb * 32 + 4);
                bf16x8 a;
                a[0]=f2bf(x.x); a[1]=f2bf(x.y); a[2]=f2bf(x.z); a[3]=f2bf(x.w);
                a[4]=f2bf(y.x); a[5]=f2bf(y.y); a[6]=f2bf(y.z); a[7]=f2bf(y.w);
                acc = __builtin_amdgcn_mfma_f32_16x16x32_bf16(a, qb[kb], acc, 0, 0, 0);
            }
            {
                int tbase = w * 16 + quad * 4;
                f32x4 sv;
                #pragma unroll
                for (int r = 0; r < 4; ++r) {
                    bool valid = (t0 + tbase + r) < ntok;
                    sv[r] = valid ? acc[r] * SCALE : -1e30f;
                }
                *(f32x4*)&St[l16][tbase] = sv;   // St[head][tok]
            }
            __syncthreads();   // S1: St ready

            if (tid < 64) {
                int h = tid >> 2, seg = tid & 3;
                const f32x4* sp = (const f32x4*)&St[h][seg * 16];
                float m = -1e30f;
                #pragma unroll
                for (int c = 0; c < 4; ++c) {
                    f32x4 x = sp[c];
                    m = fmaxf(m, fmaxf(fmaxf(x[0], x[1]), fmaxf(x[2], x[3])));
                }
                red[h][seg] = m;
            }
            __syncthreads();   // S2

            if (tid < 16) {
                float tm = fmaxf(fmaxf(red[tid][0], red[tid][1]), fmaxf(red[tid][2], red[tid][3]));
                float mo = mls[tid];
                float mn = fmaxf(mo, tm);
                alph[tid] = __expf(mo - mn);
                mls[tid] = mn;
            }
            __syncthreads();   // S3: mls/alph ready

            {
                int h = tid >> 4, c0 = (tid & 15) * 4;
                f32x4 svv = *(const f32x4*)&St[h][c0];
                float mh = mls[h];
                float e0 = __expf(svv[0] - mh), e1 = __expf(svv[1] - mh);
                float e2 = __expf(svv[2] - mh), e3 = __expf(svv[3] - mh);
                short4v pv; pv[0]=f2bf(e0); pv[1]=f2bf(e1); pv[2]=f2bf(e2); pv[3]=f2bf(e3);
                *(short4v*)&Pt[h][c0] = pv;
                Ssum[h][tid & 15] = e0 + e1 + e2 + e3;
            }
            __syncthreads();   // S4: Pt/Ssum ready

            if (tid < 16) {
                float sacc = 0.f;
                #pragma unroll
                for (int i = 0; i < 16; ++i) sacc += Ssum[tid][i];
                lls[tid] = lls[tid] * alph[tid] + sacc;
            }

            // ---- PV: D[head 16][d 16], A = P, B = V ----
            {
                float al[4];
                #pragma unroll
                for (int r = 0; r < 4; ++r) al[r] = alph[quad * 4 + r];
                #pragma unroll
                for (int r = 0; r < 4; ++r) { o0[r] *= al[r]; o1[r] *= al[r]; }
                int d0 = w * 32 + l16;
                #pragma unroll
                for (int kb = 0; kb < 2; ++kb) {
                    bf16x8 pa = *(const bf16x8*)&Pt[l16][kb * 32 + quad * 8];
                    int tloc = t0 + kb * 32 + quad * 8;
                    bf16x8 vb0, vb1;
                    #pragma unroll
                    for (int j = 0; j < 8; ++j) {
                        int f = tloc + j;
                        int tj;
                        if (useList) tj = jl[f];
                        else         tj = j0 + (f < ntok ? f : 0);
                        const float* vp = &vv[(tj * HK + n) * DV];
                        vb0[j] = f2bf(vp[d0]);
                        vb1[j] = f2bf(vp[d0 + 16]);
                    }
                    o0 = __builtin_amdgcn_mfma_f32_16x16x32_bf16(pa, vb0, o0, 0, 0, 0);
                    o1 = __builtin_amdgcn_mfma_f32_16x16x32_bf16(pa, vb1, o1, 0, 0, 0);
                }
            }
            // no end-of-tile barrier needed: next-tile writes to St/Pt/Ssum/alph are
            // separated from this tile's readers by S1..S3 of the next iteration
        }
        __syncthreads();   // lls final, accumulators done
    };

    // ---- pass A: selected tokens ----
    run_pass(tot, true);
    {
        int d0 = w * 32 + l16;
        #pragma unroll
        for (int r = 0; r < 4; ++r) {
            int h = quad * 4 + r;
            if (h < GQ) {
                float invl = 1.f / lls[h];
                Osel[h][d0]      = o0[r] * invl;
                Osel[h][d0 + 16] = o1[r] * invl;
            }
        }
    }
    __syncthreads();   // protect lls before pass-B reinit

    // ---- pass B: sliding window ----
    run_pass(wcnt, false);
    {
        int d0 = w * 32 + l16;
        #pragma unroll
        for (int r = 0; r < 4; ++r) {
            int h = quad * 4 + r;
            if (h < GQ) {
                float invl = 1.f / lls[h];
                float ow0 = o0[r] * invl;
                float ow1 = o1[r] * invl;
                int ob = (s * HQ + n * GQ + h) * DV;
                out[ob + d0]      = g3v[h][0] * cmpo[ob + d0]      + g3v[h][1] * Osel[h][d0]      + g3v[h][2] * ow0;
                out[ob + d0 + 16] = g3v[h][0] * cmpo[ob + d0 + 16] + g3v[h][1] * Osel[h][d0 + 16] + g3v[h][2] * ow1;
            }
        }
    }
}

extern "C" void kernel_launch(void* const* d_in, const int* in_sizes, int n_in,
                              void* d_out, int out_size, void* d_ws, size_t ws_size,
                              hipStream_t stream) {
    const float* q   = (const float*)d_in[0];
    const float* k   = (const float*)d_in[1];
    const float* v   = (const float*)d_in[2];
    const float* wck = (const float*)d_in[3];
    const float* wcv = (const float*)d_in[4];
    const float* wg  = (const float*)d_in[5];
    const float* bg  = (const float*)d_in[6];
    float* out = (float*)d_out;

    float* cmpk   = (float*)d_ws;                       // TT*HK*DD floats
    float* cmpv   = cmpk + TT * HK * DD;                // TT*HK*DV floats
    int*   selcnt = (int*)(cmpv + TT * HK * DV);        // HK*SS ints
    int*   selidx = selcnt + HK * SS;                   // HK*SS*TOPN ints
    float* cmpo   = (float*)(selidx + HK * SS * TOPN);  // SS*HQ*DV floats (16 MB)

    k_compress<<<dim3(TT, HK), 128, 0, stream>>>(k, v, wck, wcv, cmpk, cmpv);
    k_cmp_attn<<<HK * SS, 256, 0, stream>>>(q, cmpk, cmpv, cmpo, selcnt, selidx);
    k_main<<<dim3(SS, HK), 256, 0, stream>>>(q, k, v, wg, bg, cmpo, selcnt, selidx, out);
}

// Round 4
// 573.957 us; speedup vs baseline: 5.1560x; 1.2457x over previous
//
#include <hip/hip_runtime.h>

#define SS   2048
#define HQ   16
#define HK   2
#define GQ   8      // Hq/Hk
#define DD   128
#define DV   128
#define KS   32
#define ST   16
#define SELB 64
#define TOPN 16
#define WINW 512
#define TT   127    // (S-KS)/ST + 1
#define NSEL 32     // S/SEL
#define SCALE 0.08838834764831845f  // 1/sqrt(128)

typedef __attribute__((ext_vector_type(8))) short bf16x8;
typedef __attribute__((ext_vector_type(4))) short short4v;
typedef __attribute__((ext_vector_type(4))) float f32x4;

__device__ __forceinline__ short f2bf(float x) {
    union { float f; unsigned u; } a; a.f = x;
    unsigned r = a.u + 0x7FFFu + ((a.u >> 16) & 1u);
    return (short)(r >> 16);
}
__device__ __forceinline__ float bf2f(short b) {
    union { unsigned u; float f; } x; x.u = ((unsigned)(unsigned short)b) << 16; return x.f;
}

// ---------------- kernel 0: prep (bf16 K, transposed bf16 V, cmpk fp32, cmpvT bf16) ----------------
#define NB_K   ((SS*HK*DD)/256)    // 2048
#define NB_VT  ((SS*HK*DD)/256)    // 2048
#define NB_CK  ((TT*HK*DD)/256)    // 127
#define NB_CVT ((HK*DD*128)/256)   // 128

__global__ __launch_bounds__(256) void k_prep(
    const float* __restrict__ k, const float* __restrict__ v,
    const float* __restrict__ wck, const float* __restrict__ wcv,
    short* __restrict__ kbf, short* __restrict__ vTbf,
    float* __restrict__ cmpk, short* __restrict__ cmpvT)
{
    int bid = blockIdx.x, tid = threadIdx.x;
    if (bid < NB_K) {
        int i = bid * 256 + tid;
        kbf[i] = f2bf(k[i]);                       // same layout [tok][n][d]
    } else if (bid < NB_K + NB_VT) {
        int i = (bid - NB_K) * 256 + tid;          // [n][d][t]
        int n = i >> 18;                           // /(DD*SS)
        int r = i & ((1 << 18) - 1);
        int d = r >> 11;                           // /SS
        int t = r & (SS - 1);
        vTbf[i] = f2bf(v[(t * HK + n) * DV + d]);
    } else if (bid < NB_K + NB_VT + NB_CK) {
        int i = (bid - NB_K - NB_VT) * 256 + tid;  // (t*HK+n)*DD+d
        int t = i >> 8;
        int r = i & 255;
        int n = r >> 7, d = r & 127;
        float a = 0.f;
        #pragma unroll
        for (int j = 0; j < KS; ++j) a += k[((t * ST + j) * HK + n) * DD + d] * wck[j];
        cmpk[i] = a;
    } else {
        int i = (bid - NB_K - NB_VT - NB_CK) * 256 + tid;   // (n*DD+d)*128+tt
        int n = i >> 14;
        int r = i & 16383;
        int d = r >> 7, tt = r & 127;
        float a = 0.f;
        if (tt < TT) {
            #pragma unroll
            for (int j = 0; j < KS; ++j) a += v[((tt * ST + j) * HK + n) * DV + d] * wcv[j];
        }
        cmpvT[i] = f2bf(a);        // tt==127 zero pad
    }
}

// ---------------- kernel 1: compressed attention + block selection ----------------
__global__ __launch_bounds__(256) void k_cmp_attn(
    const float* __restrict__ q,
    const float* __restrict__ cmpk, const short* __restrict__ cmpvT,
    short* __restrict__ cmpo, int* __restrict__ selcnt, int* __restrict__ selidx)
{
    int s = blockIdx.x;
    int n = blockIdx.y;
    int tid = threadIdx.x;
    int w = tid >> 6, lane = tid & 63, quad = lane >> 4, l16 = lane & 15;

    __shared__ float qs[GQ][DD];      // 4 KB
    __shared__ float p[GQ][128];      // 4 KB (normalized fp32, for pslc)
    __shared__ short Pt[16][136];     // 4.25 KB bf16 P, rows 8-15 zero
    __shared__ float pslc[NSEL];

    for (int i = tid; i < GQ * DD; i += 256)
        qs[i >> 7][i & 127] = q[(s * HQ + n * GQ + (i >> 7)) * DD + (i & 127)];
    for (int i = tid; i < 8 * 136; i += 256)
        Pt[8 + i / 136][i % 136] = 0;
    __syncthreads();

    int tmax = (s >= KS - 1) ? ((s - (KS - 1)) / ST) : -1;
    if (tmax > TT - 1) tmax = TT - 1;
    int ntt = tmax + 1;

    // scores fp32 (exact path feeding selection): group g = tid>>5, 32 threads per g
    {
        int g = tid >> 5;
        const f32x4* qp = (const f32x4*)&qs[g][0];
        for (int t = tid & 31; t < ntt; t += 32) {
            const f32x4* ck = (const f32x4*)&cmpk[(t * HK + n) * DD];
            float a = 0.f;
            #pragma unroll 8
            for (int c = 0; c < DD / 4; ++c) {
                f32x4 kv = ck[c], qv = qp[c];
                a += qv[0] * kv[0] + qv[1] * kv[1] + qv[2] * kv[2] + qv[3] * kv[3];
            }
            p[g][t] = a * SCALE;
        }
    }
    __syncthreads();

    // wave-parallel softmax: wave w handles g = w and g = w+4
    #pragma unroll
    for (int gi = 0; gi < 2; ++gi) {
        int g = w + gi * 4;
        int t1 = lane, t2 = lane + 64;
        float v1 = (t1 < ntt) ? p[g][t1] : -1e30f;
        float v2 = (t2 < ntt) ? p[g][t2] : -1e30f;
        float m = fmaxf(v1, v2);
        #pragma unroll
        for (int o = 32; o > 0; o >>= 1) m = fmaxf(m, __shfl_xor(m, o, 64));
        float e1 = (t1 < ntt) ? __expf(v1 - m) : 0.f;
        float e2 = (t2 < ntt) ? __expf(v2 - m) : 0.f;
        float ssum = e1 + e2;
        #pragma unroll
        for (int o = 32; o > 0; o >>= 1) ssum += __shfl_xor(ssum, o, 64);
        float inv = (ntt > 0) ? (1.f / ssum) : 0.f;
        e1 *= inv; e2 *= inv;
        p[g][t1] = e1; p[g][t2] = e2;
        Pt[g][t1] = f2bf(e1); Pt[g][t2] = f2bf(e2);
    }
    __syncthreads();

    // selection-block scores
    if (tid < NSEL) {
        int m = tid;
        float a = 0.f;
        for (int dt = -1; dt < 4; ++dt) {
            int t = 4 * m + dt;
            if (t < 0 || t >= TT) continue;
            bool maps = (t / 4 == m) || ((t % 4 == 3) && (t / 4 == m - 1));
            if (!maps) continue;
            for (int g = 0; g < GQ; ++g) a += p[g][t];
        }
        pslc[m] = a;
    }
    __syncthreads();

    // top-k exactly as jax.lax.top_k (thread 0; waves 1-3 start PV meanwhile)
    if (tid == 0) {
        int cur = s / SELB;
        float score[NSEL];
        for (int m = 0; m < NSEL; ++m) {
            float sv;
            if (m == 0 || m == cur) sv = 1e30f;
            else if (m * SELB <= s) sv = pslc[m];
            else sv = -1e30f;
            score[m] = sv;
        }
        int cnt = 0;
        int* outp = &selidx[(n * SS + s) * TOPN];
        for (int pick = 0; pick < TOPN; ++pick) {
            int best = 0; float bv = -1e31f;
            for (int m = 0; m < NSEL; ++m)
                if (score[m] > bv) { bv = score[m]; best = m; }
            if (bv > -5e29f) outp[cnt++] = best;
            score[best] = -1e31f;
        }
        selcnt[n * SS + s] = cnt;
    }

    // PV via MFMA: D[head][d], A = P (LDS), B = cmpvT (global 16B loads)
    {
        f32x4 o0 = {0.f,0.f,0.f,0.f}, o1 = o0;
        int d0 = w * 32 + l16;
        const short* vrow = &cmpvT[(n * DD + d0) * 128];
        #pragma unroll
        for (int kb = 0; kb < 4; ++kb) {
            bf16x8 pa = *(const bf16x8*)&Pt[l16][kb * 32 + quad * 8];
            bf16x8 vb0 = *(const bf16x8*)(vrow + kb * 32 + quad * 8);
            bf16x8 vb1 = *(const bf16x8*)(vrow + 16 * 128 + kb * 32 + quad * 8);
            o0 = __builtin_amdgcn_mfma_f32_16x16x32_bf16(pa, vb0, o0, 0, 0, 0);
            o1 = __builtin_amdgcn_mfma_f32_16x16x32_bf16(pa, vb1, o1, 0, 0, 0);
        }
        #pragma unroll
        for (int r = 0; r < 4; ++r) {
            int h = quad * 4 + r;
            if (h < GQ) {
                int base = (s * HQ + n * GQ + h) * DV;
                cmpo[base + d0]      = f2bf(o0[r]);
                cmpo[base + d0 + 16] = f2bf(o1[r]);
            }
        }
    }
}

// ---------------- kernel 2: MFMA flash attention, block-tiled (selected + window) ----------------
__global__ __launch_bounds__(256) void k_main(
    const float* __restrict__ q, const short* __restrict__ kbf, const short* __restrict__ vTbf,
    const float* __restrict__ wg, const float* __restrict__ bg,
    const short* __restrict__ cmpo, const int* __restrict__ selcnt, const int* __restrict__ selidx,
    float* __restrict__ out)
{
    int s = blockIdx.x;
    int n = blockIdx.y;
    int tid = threadIdx.x;
    int w = tid >> 6, lane = tid & 63, quad = lane >> 4, l16 = lane & 15;

    __shared__ float St[16][68];       // score tile [head][token]
    __shared__ short Pt[16][72];       // P tile bf16
    __shared__ float red[16][4];
    __shared__ float Ssum[16][16];
    __shared__ float mls[16], lls[16], alph[16];
    __shared__ float Osel[GQ][DV];
    __shared__ float g3v[GQ][3];
    __shared__ int   sBase[TOPN];
    __shared__ int   shCnt;

    if (tid == 0) shCnt = selcnt[n * SS + s];
    if (tid >= 32 && tid < 32 + TOPN)
        sBase[tid - 32] = selidx[(n * SS + s) * TOPN + (tid - 32)] * SELB;
    if (tid >= 64 && tid < 64 + GQ * 3) {
        int gg = (tid - 64) / 3, c = (tid - 64) % 3;
        const float* qp = &q[(s * HQ + n * GQ + gg) * DD];
        float a = 0.f;
        for (int d2 = 0; d2 < DD; ++d2) a += qp[d2] * wg[d2 * 3 + c];
        a += bg[c];
        g3v[gg][c] = 1.f / (1.f + __expf(-a));
    }

    // Q B-fragments: head = l16, features kb*32 + quad*8 + j
    bf16x8 qb[4];
    {
        int h = l16;
        if (h < GQ) {
            const float* qp = &q[(s * HQ + n * GQ + h) * DD + quad * 8];
            #pragma unroll
            for (int kb = 0; kb < 4; ++kb) {
                f32x4 x = *(const f32x4*)(qp + kb * 32);
                f32x4 y = *(const f32x4*)(qp + kb * 32 + 4);
                bf16x8 t;
                t[0]=f2bf(x[0]); t[1]=f2bf(x[1]); t[2]=f2bf(x[2]); t[3]=f2bf(x[3]);
                t[4]=f2bf(y[0]); t[5]=f2bf(y[1]); t[6]=f2bf(y[2]); t[7]=f2bf(y[3]);
                qb[kb] = t;
            }
        } else {
            #pragma unroll
            for (int kb = 0; kb < 4; ++kb) { bf16x8 z = {0,0,0,0,0,0,0,0}; qb[kb] = z; }
        }
    }
    __syncthreads();
    int cnt = shCnt;
    int j0 = (s >= WINW) ? (s - WINW) : 0;
    int tb0 = j0 & ~63;
    int ntB = ((s - tb0) >> 6) + 1;

    f32x4 o0, o1;

    auto run_pass = [&](int nTiles, bool selPass) {
        f32x4 z = {0.f, 0.f, 0.f, 0.f};
        o0 = z; o1 = z;
        if (tid < 16) { mls[tid] = -1e30f; lls[tid] = 0.f; }
        __syncthreads();

        for (int ti = 0; ti < nTiles; ++ti) {
            int tstart = selPass ? sBase[ti] : (tb0 + ti * 64);
            int loT = selPass ? tstart : ((tstart > j0) ? tstart : j0);
            int hiT = (tstart + 63 < s) ? (tstart + 63) : s;

            // ---- scores: A = K rows (m = token), B = Q (nn = head) ----
            f32x4 acc = z;
            {
                int tokA = tstart + w * 16 + l16;
                const short* kp = &kbf[(tokA * HK + n) * DD + quad * 8];
                #pragma unroll
                for (int kb = 0; kb < 4; ++kb) {
                    bf16x8 a = *(const bf16x8*)(kp + kb * 32);
                    acc = __builtin_amdgcn_mfma_f32_16x16x32_bf16(a, qb[kb], acc, 0, 0, 0);
                }
            }
            {
                int tbase = w * 16 + quad * 4;
                f32x4 sv;
                #pragma unroll
                for (int r = 0; r < 4; ++r) {
                    int tok = tstart + tbase + r;
                    sv[r] = (tok >= loT && tok <= hiT) ? acc[r] * SCALE : -1e30f;
                }
                *(f32x4*)&St[l16][tbase] = sv;
            }
            __syncthreads();   // S1

            if (tid < 64) {
                int h = tid >> 2, seg = tid & 3;
                const f32x4* sp = (const f32x4*)&St[h][seg * 16];
                float m = -1e30f;
                #pragma unroll
                for (int c = 0; c < 4; ++c) {
                    f32x4 x = sp[c];
                    m = fmaxf(m, fmaxf(fmaxf(x[0], x[1]), fmaxf(x[2], x[3])));
                }
                red[h][seg] = m;
            }
            __syncthreads();   // S2

            if (tid < 16) {
                float tm = fmaxf(fmaxf(red[tid][0], red[tid][1]), fmaxf(red[tid][2], red[tid][3]));
                float mo = mls[tid];
                float mn = fmaxf(mo, tm);
                alph[tid] = __expf(mo - mn);
                mls[tid] = mn;
            }
            __syncthreads();   // S3

            {
                int h = tid >> 4, c0 = (tid & 15) * 4;
                f32x4 svv = *(const f32x4*)&St[h][c0];
                float mh = mls[h];
                float e0 = __expf(svv[0] - mh), e1 = __expf(svv[1] - mh);
                float e2 = __expf(svv[2] - mh), e3 = __expf(svv[3] - mh);
                short4v pv; pv[0]=f2bf(e0); pv[1]=f2bf(e1); pv[2]=f2bf(e2); pv[3]=f2bf(e3);
                *(short4v*)&Pt[h][c0] = pv;
                Ssum[h][tid & 15] = e0 + e1 + e2 + e3;
            }
            __syncthreads();   // S4

            if (tid < 16) {
                float sacc = 0.f;
                #pragma unroll
                for (int i = 0; i < 16; ++i) sacc += Ssum[tid][i];
                lls[tid] = lls[tid] * alph[tid] + sacc;
            }

            // ---- PV: A = P (LDS), B = V from transposed bf16 (16B loads) ----
            {
                float al[4];
                #pragma unroll
                for (int r = 0; r < 4; ++r) al[r] = alph[quad * 4 + r];
                #pragma unroll
                for (int r = 0; r < 4; ++r) { o0[r] *= al[r]; o1[r] *= al[r]; }
                int d0 = w * 32 + l16;
                const short* vrow = &vTbf[(n * DD + d0) * SS];
                #pragma unroll
                for (int kb = 0; kb < 2; ++kb) {
                    bf16x8 pa = *(const bf16x8*)&Pt[l16][kb * 32 + quad * 8];
                    int tj = tstart + kb * 32 + quad * 8;
                    bf16x8 vb0 = *(const bf16x8*)(vrow + tj);
                    bf16x8 vb1 = *(const bf16x8*)(vrow + 16 * SS + tj);
                    o0 = __builtin_amdgcn_mfma_f32_16x16x32_bf16(pa, vb0, o0, 0, 0, 0);
                    o1 = __builtin_amdgcn_mfma_f32_16x16x32_bf16(pa, vb1, o1, 0, 0, 0);
                }
            }
        }
        __syncthreads();
    };

    // ---- pass A: selected blocks ----
    run_pass(cnt, true);
    {
        int d0 = w * 32 + l16;
        #pragma unroll
        for (int r = 0; r < 4; ++r) {
            int h = quad * 4 + r;
            if (h < GQ) {
                float invl = 1.f / lls[h];
                Osel[h][d0]      = o0[r] * invl;
                Osel[h][d0 + 16] = o1[r] * invl;
            }
        }
    }
    __syncthreads();

    // ---- pass B: sliding window ----
    run_pass(ntB, false);
    {
        int d0 = w * 32 + l16;
        #pragma unroll
        for (int r = 0; r < 4; ++r) {
            int h = quad * 4 + r;
            if (h < GQ) {
                float invl = 1.f / lls[h];
                float ow0 = o0[r] * invl;
                float ow1 = o1[r] * invl;
                int ob = (s * HQ + n * GQ + h) * DV;
                out[ob + d0]      = g3v[h][0] * bf2f(cmpo[ob + d0])      + g3v[h][1] * Osel[h][d0]      + g3v[h][2] * ow0;
                out[ob + d0 + 16] = g3v[h][0] * bf2f(cmpo[ob + d0 + 16]) + g3v[h][1] * Osel[h][d0 + 16] + g3v[h][2] * ow1;
            }
        }
    }
}

extern "C" void kernel_launch(void* const* d_in, const int* in_sizes, int n_in,
                              void* d_out, int out_size, void* d_ws, size_t ws_size,
                              hipStream_t stream) {
    const float* q   = (const float*)d_in[0];
    const float* k   = (const float*)d_in[1];
    const float* v   = (const float*)d_in[2];
    const float* wck = (const float*)d_in[3];
    const float* wcv = (const float*)d_in[4];
    const float* wg  = (const float*)d_in[5];
    const float* bg  = (const float*)d_in[6];
    float* out = (float*)d_out;

    float* cmpk   = (float*)d_ws;                       // TT*HK*DD f32
    int*   selcnt = (int*)(cmpk + TT * HK * DD);        // HK*SS
    int*   selidx = selcnt + HK * SS;                   // HK*SS*TOPN
    short* cmpo   = (short*)(selidx + HK * SS * TOPN);  // SS*HQ*DV bf16 (8 MB)
    short* kbf    = cmpo + SS * HQ * DV;                // SS*HK*DD bf16 (1 MB)
    short* vTbf   = kbf + SS * HK * DD;                 // HK*DD*SS bf16 (1 MB)
    short* cmpvT  = vTbf + SS * HK * DD;                // HK*DD*128 bf16 (64 KB)

    k_prep<<<NB_K + NB_VT + NB_CK + NB_CVT, 256, 0, stream>>>(k, v, wck, wcv, kbf, vTbf, cmpk, cmpvT);
    k_cmp_attn<<<dim3(SS, HK), 256, 0, stream>>>(q, cmpk, cmpvT, cmpo, selcnt, selidx);
    k_main<<<dim3(SS, HK), 256, 0, stream>>>(q, kbf, vTbf, wg, bg, cmpo, selcnt, selidx, out);
}